// Round 1
// baseline (887.874 us; speedup 1.0000x reference)
//
#include <hip/hip_runtime.h>
#include <stdint.h>
#include <stddef.h>

#define BATCH 65536
#define DIN   256
#define HDIM  512
#define KDIM  768           // Din + H
#define NDIM  2048          // 4*H, gate-interleaved packing
#define HN_ELEMS (BATCH * HDIM)

using f32x4 = __attribute__((ext_vector_type(4))) float;
using s16x8 = __attribute__((ext_vector_type(8))) short;
using u16x8 = __attribute__((ext_vector_type(8))) unsigned short;
using u32x4 = __attribute__((ext_vector_type(4))) unsigned int;

__device__ __forceinline__ unsigned short f2bf(float f) {
    union { float f; unsigned u; } v; v.f = f;
    unsigned r = v.u + 0x7fffu + ((v.u >> 16) & 1u);   // RNE
    return (unsigned short)(r >> 16);
}

// packed f32x2 -> bf16x2 (lo = src0, hi = src1), RNE. No builtin on gfx950 (m240).
__device__ __forceinline__ unsigned pk2(float lo, float hi) {
    unsigned r;
    asm("v_cvt_pk_bf16_f32 %0, %1, %2" : "=v"(r) : "v"(lo), "v"(hi));
    return r;
}

// ---------------------------------------------------------------------------
// Pack weights bf16 B^T: wPack[n][k]. n = (h>>4)*64 + g*16 + (h&15).
// ---------------------------------------------------------------------------
__global__ __launch_bounds__(256) void pack_w_kernel(
    const float* __restrict__ U, const float* __restrict__ W,
    unsigned short* __restrict__ wPack)
{
    int idx = blockIdx.x * 256 + threadIdx.x;   // 2048*96 = 196608 threads
    int n = idx / 96;
    int seg = idx - n * 96;
    int k0 = seg * 8;
    int g = (n >> 4) & 3;
    int h = ((n >> 6) << 4) | (n & 15);
    u16x8 o;
    if (k0 < DIN) {
        const float* src = U + ((size_t)g * DIN + k0) * HDIM + h;
#pragma unroll
        for (int kk = 0; kk < 8; ++kk) o[kk] = f2bf(src[(size_t)kk * HDIM]);
    } else {
        const float* src = W + ((size_t)g * HDIM + (k0 - DIN)) * HDIM + h;
#pragma unroll
        for (int kk = 0; kk < 8; ++kk) o[kk] = f2bf(src[(size_t)kk * HDIM]);
    }
    *(u16x8*)(wPack + (size_t)n * KDIM + k0) = o;
}

__global__ __launch_bounds__(256) void pack_bias_kernel(
    const float* __restrict__ bU, const float* __restrict__ bW,
    float* __restrict__ bias)
{
    int n = blockIdx.x * 256 + threadIdx.x;   // 2048 total
    int g = (n >> 4) & 3;
    int h = ((n >> 6) << 4) | (n & 15);
    bias[n] = bU[g * HDIM + h] + bW[g * HDIM + h];
}

// ---------------------------------------------------------------------------
// Fused pack(A f32->bf16) + GEMM + LSTM epilogue.
// 256x256 tile, BK=64, 512 threads = 8 waves (2M x 4N), wave tile 128x64.
// Double-buffered LDS: A[2][256][64] | B[2][256][64] bf16 = 128 KB.
// XOR swizzle: within a 128B LDS row, 16B chunk c of row r stored at slot
// c ^ (r&7). A is written by cvt+ds_write (swizzle on write addr); B is
// global_load_lds with pre-swizzled per-lane GLOBAL source, linear LDS dest.
// ---------------------------------------------------------------------------
__global__ __launch_bounds__(512, 2) void lstm_fused_kernel(
    const float* __restrict__ x,
    const float* __restrict__ hOld,
    const unsigned short* __restrict__ wPack,
    const float* __restrict__ bias,
    const float* __restrict__ cOld,
    float* __restrict__ out)
{
    __shared__ __align__(16) unsigned short smem[65536];   // 128 KB

    const int tid = threadIdx.x;
    const int w  = tid >> 6;          // wave 0..7
    const int l  = tid & 63;
    const int wm = w >> 2;            // 0..1  (M wave grid)
    const int wn = w & 3;             // 0..3  (N wave grid)
    const int lq = l >> 4;            // quad 0..3
    const int lc = l & 15;

    // bijective XCD swizzle: nwg = 2048, 8 XCDs, 256 wgs per XCD chunk.
    const int bid = blockIdx.x;
    const int wg  = (bid & 7) * 256 + (bid >> 3);
    const int mt  = wg >> 3;          // 0..255
    const int nt  = wg & 7;           // 0..7
    const int m0  = mt * 256;
    const int n0  = nt * 256;

    // ---- A staging mapping: thread -> (row ar, f32 col half ah*32) ----
    const int ar = tid >> 1;          // 0..255
    const int ah = tid & 1;
    const float* xrow = x    + (size_t)(m0 + ar) * DIN  + ah * 32;
    const float* hrow = hOld + (size_t)(m0 + ar) * HDIM + ah * 32;
    const int awsw = ar & 7;          // write-side swizzle key

    // ---- B staging mapping: per-lane pre-swizzled global source ----
    const int brow   = w * 32 + (l >> 3);              // + q*8
    const int bchunk = (l & 7) ^ ((l >> 3) & 7);       // global chunk for lane
    const unsigned short* bsrc = wPack + (size_t)(n0 + brow) * KDIM + bchunk * 8;

    f32x4 acc[8][4];
#pragma unroll
    for (int i = 0; i < 8; ++i)
#pragma unroll
        for (int j = 0; j < 4; ++j)
            acc[i][j] = (f32x4){0.f, 0.f, 0.f, 0.f};

    // ---- prologue: stage kt=0 into buffer 0 ----
    {
        f32x4 av[8];
#pragma unroll
        for (int u = 0; u < 8; ++u) av[u] = ((const f32x4*)xrow)[u];   // kt=0 -> x
#pragma unroll
        for (int q = 0; q < 4; ++q) {
            const unsigned short* gb = bsrc + (size_t)q * 8 * KDIM;
            __builtin_amdgcn_global_load_lds(
                (const __attribute__((address_space(1))) void*)gb,
                (__attribute__((address_space(3))) void*)&smem[32768 + (w * 32 + q * 8) * 64],
                16, 0, 0);
        }
#pragma unroll
        for (int u = 0; u < 4; ++u) {
            u32x4 o;
            o[0] = pk2(av[2 * u][0],     av[2 * u][1]);
            o[1] = pk2(av[2 * u][2],     av[2 * u][3]);
            o[2] = pk2(av[2 * u + 1][0], av[2 * u + 1][1]);
            o[3] = pk2(av[2 * u + 1][2], av[2 * u + 1][3]);
            *(u32x4*)&smem[ar * 64 + (((ah * 4 + u) ^ awsw) << 3)] = o;
        }
    }
    __syncthreads();

    // ---- main K loop: 12 steps of BK=64 (k<256 from x, else from h_old) ----
#pragma unroll
    for (int kt = 0; kt < 12; ++kt) {
        const int cur = kt & 1;
        const int nxt = cur ^ 1;

        f32x4 av[8];
        if (kt < 11) {
            const float* s = (kt + 1 < 4) ? (xrow + (kt + 1) * 64)
                                          : (hrow + (kt - 3) * 64);
#pragma unroll
            for (int u = 0; u < 8; ++u) av[u] = ((const f32x4*)s)[u];
#pragma unroll
            for (int q = 0; q < 4; ++q) {
                const unsigned short* gb = bsrc + (size_t)q * 8 * KDIM + (kt + 1) * 64;
                __builtin_amdgcn_global_load_lds(
                    (const __attribute__((address_space(1))) void*)gb,
                    (__attribute__((address_space(3))) void*)&smem[32768 + nxt * 16384 + (w * 32 + q * 8) * 64],
                    16, 0, 0);
            }
        }

        // compute on cur
        {
            const int aoff = cur * 16384 + (wm * 128 + lc) * 64;
            const int boff = 32768 + cur * 16384 + (wn * 64 + lc) * 64;
            const int sx = lc & 7;
#pragma unroll
            for (int ks = 0; ks < 2; ++ks) {
                const int slot = (((ks * 4 + lq) ^ sx)) << 3;
                s16x8 af[8], bf4[4];
#pragma unroll
                for (int i = 0; i < 8; ++i)
                    af[i] = *(const s16x8*)&smem[aoff + i * 1024 + slot];
#pragma unroll
                for (int j = 0; j < 4; ++j)
                    bf4[j] = *(const s16x8*)&smem[boff + j * 1024 + slot];
#pragma unroll
                for (int i = 0; i < 8; ++i)
#pragma unroll
                    for (int j = 0; j < 4; ++j)
                        acc[i][j] = __builtin_amdgcn_mfma_f32_16x16x32_bf16(
                            af[i], bf4[j], acc[i][j], 0, 0, 0);
            }
        }

        if (kt < 11) {
#pragma unroll
            for (int u = 0; u < 4; ++u) {
                u32x4 o;
                o[0] = pk2(av[2 * u][0],     av[2 * u][1]);
                o[1] = pk2(av[2 * u][2],     av[2 * u][3]);
                o[2] = pk2(av[2 * u + 1][0], av[2 * u + 1][1]);
                o[3] = pk2(av[2 * u + 1][2], av[2 * u + 1][3]);
                *(u32x4*)&smem[nxt * 16384 + ar * 64 + (((ah * 4 + u) ^ awsw) << 3)] = o;
            }
        }
        __syncthreads();
    }

    // ---- epilogue: j = gate (i,f,o,c); LDS-transposed full-line stores ----
    const int nbase = n0 + wn * 64;
    const float b0 = bias[nbase +  0 + lc];
    const float b1 = bias[nbase + 16 + lc];
    const float b2 = bias[nbase + 32 + lc];
    const float b3 = bias[nbase + 48 + lc];
    const int hcol = (n0 >> 2) + wn * 16 + lc;

    float co[8][4];
#pragma unroll
    for (int i = 0; i < 8; ++i)
#pragma unroll
        for (int r = 0; r < 4; ++r)
            co[i][r] = cOld[(size_t)(m0 + wm * 128 + i * 16 + lq * 4 + r) * HDIM + hcol];

    float* fsm  = (float*)smem;
    float* hn_t = fsm;            // 64 cols x stride 36 = 2304 floats
    float* cn_t = fsm + 2304;

#pragma unroll
    for (int i = 0; i < 8; ++i) {
        f32x4 hnv, cnv;
#pragma unroll
        for (int r = 0; r < 4; ++r) {
            const float gi = acc[i][0][r] + b0;
            const float gf = acc[i][1][r] + b1;
            const float go = acc[i][2][r] + b2;
            const float gc = acc[i][3][r] + b3;
            const float it = 1.f / (1.f + __expf(-gi));
            const float ft = 1.f / (1.f + __expf(-gf));
            const float ot = 1.f / (1.f + __expf(-go));
            const float ct = 2.f / (1.f + __expf(-2.f * gc)) - 1.f;
            const float cn = it * ct + ft * co[i][r];
            const float tc = 2.f / (1.f + __expf(-2.f * cn)) - 1.f;
            cnv[r] = cn;
            hnv[r] = ot * tc;
        }
        __syncthreads();   // previous chunk's phase-B reads done
        {
            const int addr = (wn * 16 + lc) * 36 + wm * 16 + lq * 4;
            *(f32x4*)&hn_t[addr] = hnv;
            *(f32x4*)&cn_t[addr] = cnv;
        }
        __syncthreads();
        // phase B: 16 threads/row x 32 rows, 256B coalesced segments
        {
            const int rl = tid >> 4;            // 0..31
            const int cg = tid & 15;            // 0..15 -> 4 cols each
            const int grow = m0 + (rl >> 4) * 128 + i * 16 + (rl & 15);
            f32x4 hv, cv;
#pragma unroll
            for (int c = 0; c < 4; ++c) {
                hv[c] = hn_t[(cg * 4 + c) * 36 + rl];
                cv[c] = cn_t[(cg * 4 + c) * 36 + rl];
            }
            const size_t ob = (size_t)grow * HDIM + (n0 >> 2) + cg * 4;
            *(f32x4*)&out[ob] = hv;
            *(f32x4*)&out[(size_t)HN_ELEMS + ob] = cv;
        }
    }
}

extern "C" void kernel_launch(void* const* d_in, const int* in_sizes, int n_in,
                              void* d_out, int out_size, void* d_ws, size_t ws_size,
                              hipStream_t stream)
{
    const float* x     = (const float*)d_in[0];
    const float* h_old = (const float*)d_in[1];
    const float* c_old = (const float*)d_in[2];
    const float* U     = (const float*)d_in[3];
    const float* bU    = (const float*)d_in[4];
    const float* W     = (const float*)d_in[5];
    const float* bW    = (const float*)d_in[6];
    float* out = (float*)d_out;

    unsigned short* wPack = (unsigned short*)d_ws;                                 // 3 MB
    float* bias = (float*)((char*)d_ws + (size_t)NDIM * KDIM * 2);                 // 8 KB

    pack_w_kernel<<<dim3(768), dim3(256), 0, stream>>>(U, W, wPack);
    pack_bias_kernel<<<dim3(8), dim3(256), 0, stream>>>(bU, bW, bias);
    lstm_fused_kernel<<<dim3(2048), dim3(512), 0, stream>>>(x, h_old, wPack, bias, c_old, out);
}

// Round 2
// 769.817 us; speedup vs baseline: 1.1534x; 1.1534x over previous
//
#include <hip/hip_runtime.h>
#include <stdint.h>
#include <stddef.h>

#define BATCH 65536
#define DIN   256
#define HDIM  512
#define KDIM  768           // Din + H
#define NDIM  2048          // 4*H, gate-interleaved packing
#define HN_ELEMS (BATCH * HDIM)

using f32x4 = __attribute__((ext_vector_type(4))) float;
using s16x8 = __attribute__((ext_vector_type(8))) short;
using u16x8 = __attribute__((ext_vector_type(8))) unsigned short;
using u32x4 = __attribute__((ext_vector_type(4))) unsigned int;

__device__ __forceinline__ unsigned short f2bf(float f) {
    union { float f; unsigned u; } v; v.f = f;
    unsigned r = v.u + 0x7fffu + ((v.u >> 16) & 1u);   // RNE
    return (unsigned short)(r >> 16);
}

// packed f32x2 -> bf16x2 (lo = src0, hi = src1), RNE. No builtin on gfx950 (m240).
__device__ __forceinline__ unsigned pk2(float lo, float hi) {
    unsigned r;
    asm("v_cvt_pk_bf16_f32 %0, %1, %2" : "=v"(r) : "v"(lo), "v"(hi));
    return r;
}

// ---------------------------------------------------------------------------
// Pack weights bf16 B^T: wPack[n][k]. n = (h>>4)*64 + g*16 + (h&15).
// ---------------------------------------------------------------------------
__global__ __launch_bounds__(256) void pack_w_kernel(
    const float* __restrict__ U, const float* __restrict__ W,
    unsigned short* __restrict__ wPack)
{
    int idx = blockIdx.x * 256 + threadIdx.x;   // 2048*96 = 196608 threads
    int n = idx / 96;
    int seg = idx - n * 96;
    int k0 = seg * 8;
    int g = (n >> 4) & 3;
    int h = ((n >> 6) << 4) | (n & 15);
    u16x8 o;
    if (k0 < DIN) {
        const float* src = U + ((size_t)g * DIN + k0) * HDIM + h;
#pragma unroll
        for (int kk = 0; kk < 8; ++kk) o[kk] = f2bf(src[(size_t)kk * HDIM]);
    } else {
        const float* src = W + ((size_t)g * HDIM + (k0 - DIN)) * HDIM + h;
#pragma unroll
        for (int kk = 0; kk < 8; ++kk) o[kk] = f2bf(src[(size_t)kk * HDIM]);
    }
    *(u16x8*)(wPack + (size_t)n * KDIM + k0) = o;
}

__global__ __launch_bounds__(256) void pack_bias_kernel(
    const float* __restrict__ bU, const float* __restrict__ bW,
    float* __restrict__ bias)
{
    int n = blockIdx.x * 256 + threadIdx.x;   // 2048 total
    int g = (n >> 4) & 3;
    int h = ((n >> 6) << 4) | (n & 15);
    bias[n] = bU[g * HDIM + h] + bW[g * HDIM + h];
}

// ---------------------------------------------------------------------------
// Fused pack(A f32->bf16) + GEMM + LSTM epilogue.
// 128x128 tile, BK=32, 256 threads = 4 waves (2x2), wave tile 64x64.
// Double-buffered LDS (ONE barrier per K-step): A[2][128][32] | B[2][128][32]
// bf16 = 32 KB -> 3 blocks/CU with __launch_bounds__(256,3) (round-0 TLP
// regime restored; round-1's 128KB/1-block was the regression).
// A is converted in-kernel: reg-load f32 (issued before B's gl_lds so the
// wait is a counted vmcnt, not a drain), cvt_pk after MFMAs, swizzled
// ds_write_b128. B via global_load_lds with pre-swizzled global source.
// Swizzle: LDS 16B-slot p of row r holds global chunk p ^ ((r>>2)&3).
// ---------------------------------------------------------------------------
__global__ __launch_bounds__(256, 3) void lstm_fused_kernel(
    const float* __restrict__ x,
    const float* __restrict__ hOld,
    const unsigned short* __restrict__ wPack,
    const float* __restrict__ bias,
    const float* __restrict__ cOld,
    float* __restrict__ out)
{
    __shared__ __align__(16) unsigned short smem[16384];   // 32 KB

    const int tid = threadIdx.x;
    const int w  = tid >> 6;          // wave 0..3
    const int l  = tid & 63;
    const int wm = w >> 1;
    const int wn = w & 1;
    const int lq = l >> 4;            // quad 0..3
    const int lc = l & 15;

    // bijective XCD chunking: 8192 wgs, 8 XCDs, 1024/XCD; N fastest within.
    const int bid = blockIdx.x;
    const int wg  = (bid & 7) * 1024 + (bid >> 3);
    const int nt  = wg & 15;          // 0..15
    const int mt  = wg >> 4;          // 0..511
    const int m0  = mt * 128;
    const int n0  = nt * 128;

    // ---- A staging: thread -> (row ar, k-half ah*16). 16 f32 -> 2 chunks ----
    const int ar = tid >> 1;          // 0..127
    const int ah = tid & 1;
    const float* xrow = x    + (size_t)(m0 + ar) * DIN  + ah * 16;
    const float* hrow = hOld + (size_t)(m0 + ar) * HDIM + ah * 16;
    const int akey = (ar >> 2) & 3;
    const int as0 = ((ah * 2)     ^ akey) * 8;   // short offsets within row
    const int as1 = ((ah * 2 + 1) ^ akey) * 8;

    // ---- B staging: 2 gl_lds per thread; pre-swizzled global chunk ----
    const int brow_l = l >> 2;                       // 0..15
    const int bchunk = (l & 3) ^ ((l >> 4) & 3);
    const unsigned short* gb0 = wPack + (size_t)(n0 + w * 16 + brow_l) * KDIM + bchunk * 8;
    const unsigned short* gb1 = gb0 + (size_t)64 * KDIM;

    const int swz = (lc >> 2) & 3;    // fragment read-side swizzle

    f32x4 acc[4][4];
#pragma unroll
    for (int i = 0; i < 4; ++i)
#pragma unroll
        for (int j = 0; j < 4; ++j)
            acc[i][j] = (f32x4){0.f, 0.f, 0.f, 0.f};

    // ---- prologue: stage kt=0 into buffer 0 ----
    {
        f32x4 av0 = ((const f32x4*)xrow)[0];
        f32x4 av1 = ((const f32x4*)xrow)[1];
        f32x4 av2 = ((const f32x4*)xrow)[2];
        f32x4 av3 = ((const f32x4*)xrow)[3];
        __builtin_amdgcn_global_load_lds(
            (const __attribute__((address_space(1))) void*)gb0,
            (__attribute__((address_space(3))) void*)&smem[8192 + w * 512], 16, 0, 0);
        __builtin_amdgcn_global_load_lds(
            (const __attribute__((address_space(1))) void*)gb1,
            (__attribute__((address_space(3))) void*)&smem[8192 + 2048 + w * 512], 16, 0, 0);
        u32x4 o0, o1;
        o0[0] = pk2(av0[0], av0[1]); o0[1] = pk2(av0[2], av0[3]);
        o0[2] = pk2(av1[0], av1[1]); o0[3] = pk2(av1[2], av1[3]);
        o1[0] = pk2(av2[0], av2[1]); o1[1] = pk2(av2[2], av2[3]);
        o1[2] = pk2(av3[0], av3[1]); o1[3] = pk2(av3[2], av3[3]);
        *(u32x4*)&smem[ar * 32 + as0] = o0;
        *(u32x4*)&smem[ar * 32 + as1] = o1;
    }
    __syncthreads();

    // ---- main K loop: 24 steps of BK=32, dbuf, one barrier per step ----
    auto step = [&](int kt, int cur) {
        const int nxt = cur ^ 1;
        f32x4 av0, av1, av2, av3;
        const bool pf = (kt < 23);
        if (pf) {
            const int k2 = kt + 1;
            const float* s = (k2 < 8) ? (xrow + k2 * 32) : (hrow + (k2 - 8) * 32);
            av0 = ((const f32x4*)s)[0];
            av1 = ((const f32x4*)s)[1];
            av2 = ((const f32x4*)s)[2];
            av3 = ((const f32x4*)s)[3];
            const int bb = 8192 + nxt * 4096;
            __builtin_amdgcn_global_load_lds(
                (const __attribute__((address_space(1))) void*)(gb0 + k2 * 32),
                (__attribute__((address_space(3))) void*)&smem[bb + w * 512], 16, 0, 0);
            __builtin_amdgcn_global_load_lds(
                (const __attribute__((address_space(1))) void*)(gb1 + k2 * 32),
                (__attribute__((address_space(3))) void*)&smem[bb + 2048 + w * 512], 16, 0, 0);
        }
        // compute on cur
        {
            const int ab = cur * 4096;
            const int bb = 8192 + cur * 4096;
            s16x8 af[4], bf4[4];
#pragma unroll
            for (int i = 0; i < 4; ++i)
                af[i] = *(const s16x8*)&smem[ab + (wm * 64 + i * 16 + lc) * 32 + (lq ^ swz) * 8];
#pragma unroll
            for (int j = 0; j < 4; ++j)
                bf4[j] = *(const s16x8*)&smem[bb + (wn * 64 + j * 16 + lc) * 32 + (lq ^ swz) * 8];
#pragma unroll
            for (int i = 0; i < 4; ++i)
#pragma unroll
                for (int j = 0; j < 4; ++j)
                    acc[i][j] = __builtin_amdgcn_mfma_f32_16x16x32_bf16(
                        af[i], bf4[j], acc[i][j], 0, 0, 0);
        }
        if (pf) {
            u32x4 o0, o1;
            o0[0] = pk2(av0[0], av0[1]); o0[1] = pk2(av0[2], av0[3]);
            o0[2] = pk2(av1[0], av1[1]); o0[3] = pk2(av1[2], av1[3]);
            o1[0] = pk2(av2[0], av2[1]); o1[1] = pk2(av2[2], av2[3]);
            o1[2] = pk2(av3[0], av3[1]); o1[3] = pk2(av3[2], av3[3]);
            *(u32x4*)&smem[nxt * 4096 + ar * 32 + as0] = o0;
            *(u32x4*)&smem[nxt * 4096 + ar * 32 + as1] = o1;
        }
        __syncthreads();
    };
#pragma unroll 1
    for (int kt = 0; kt < 24; kt += 2) {
        step(kt, 0);
        step(kt + 1, 1);
    }

    // ---- epilogue: j = gate (i,f,o,c); LDS-transposed full-line stores ----
    const int nbase = n0 + wn * 64;
    const float b0 = bias[nbase +  0 + lc];
    const float b1 = bias[nbase + 16 + lc];
    const float b2 = bias[nbase + 32 + lc];
    const float b3 = bias[nbase + 48 + lc];
    const int hcol = (n0 >> 2) + wn * 16 + lc;

    float co[4][4];
#pragma unroll
    for (int i = 0; i < 4; ++i)
#pragma unroll
        for (int r = 0; r < 4; ++r)
            co[i][r] = cOld[(size_t)(m0 + wm * 64 + i * 16 + lq * 4 + r) * HDIM + hcol];

    float* fsm  = (float*)smem;
    float* hn_t = fsm;            // 32 cols x stride 36 = 1152 floats
    float* cn_t = fsm + 1152;     // total 9216 B < 32 KB

#pragma unroll
    for (int i = 0; i < 4; ++i) {
        f32x4 hnv, cnv;
#pragma unroll
        for (int r = 0; r < 4; ++r) {
            const float gi = acc[i][0][r] + b0;
            const float gf = acc[i][1][r] + b1;
            const float go = acc[i][2][r] + b2;
            const float gc = acc[i][3][r] + b3;
            const float it = 1.f / (1.f + __expf(-gi));
            const float ft = 1.f / (1.f + __expf(-gf));
            const float ot = 1.f / (1.f + __expf(-go));
            const float ct = 2.f / (1.f + __expf(-2.f * gc)) - 1.f;
            const float cn = it * ct + ft * co[i][r];
            const float tc = 2.f / (1.f + __expf(-2.f * cn)) - 1.f;
            cnv[r] = cn;
            hnv[r] = ot * tc;
        }
        __syncthreads();   // previous chunk's phase-B reads done
        {
            const int addr = (wn * 16 + lc) * 36 + wm * 16 + lq * 4;
            *(f32x4*)&hn_t[addr] = hnv;
            *(f32x4*)&cn_t[addr] = cnv;
        }
        __syncthreads();
        // phase B: full-line coalesced stores. 8 threads/row x 32 rows.
        {
            const int rloc = tid >> 3;          // 0..31
            const int cg   = tid & 7;           // 0..7 -> 4 cols each
            const int grow = m0 + (rloc >> 4) * 64 + i * 16 + (rloc & 15);
            f32x4 hv, cv;
#pragma unroll
            for (int c = 0; c < 4; ++c) {
                hv[c] = hn_t[(cg * 4 + c) * 36 + rloc];
                cv[c] = cn_t[(cg * 4 + c) * 36 + rloc];
            }
            const size_t ob = (size_t)grow * HDIM + (n0 >> 2) + cg * 4;
            *(f32x4*)&out[ob] = hv;
            *(f32x4*)&out[(size_t)HN_ELEMS + ob] = cv;
        }
    }
}

extern "C" void kernel_launch(void* const* d_in, const int* in_sizes, int n_in,
                              void* d_out, int out_size, void* d_ws, size_t ws_size,
                              hipStream_t stream)
{
    const float* x     = (const float*)d_in[0];
    const float* h_old = (const float*)d_in[1];
    const float* c_old = (const float*)d_in[2];
    const float* U     = (const float*)d_in[3];
    const float* bU    = (const float*)d_in[4];
    const float* W     = (const float*)d_in[5];
    const float* bW    = (const float*)d_in[6];
    float* out = (float*)d_out;

    unsigned short* wPack = (unsigned short*)d_ws;                                 // 3 MB
    float* bias = (float*)((char*)d_ws + (size_t)NDIM * KDIM * 2);                 // 8 KB

    pack_w_kernel<<<dim3(768), dim3(256), 0, stream>>>(U, W, wPack);
    pack_bias_kernel<<<dim3(8), dim3(256), 0, stream>>>(bU, bW, bias);
    lstm_fused_kernel<<<dim3(8192), dim3(256), 0, stream>>>(x, h_old, wPack, bias, c_old, out);
}